// Round 1
// baseline (1130.749 us; speedup 1.0000x reference)
//
#include <hip/hip_runtime.h>
#include <stdint.h>

#define NROWS 32768
#define KP    4000
#define DIM   128
#define CL    1000
#define NCHUNKS 8
#define KCHUNK  (KP / NCHUNKS)   // 500

// Map float to a 32-bit key with the same total order (handles negatives).
__device__ __forceinline__ unsigned int f2ord(float f) {
    unsigned int u = __float_as_uint(f);
    return (u & 0x80000000u) ? ~u : (u | 0x80000000u);
}

// p2[k] = ||proxies[k]||^2 ; packed[n] = u64 max (ws is poisoned each launch)
__global__ void init_kernel(unsigned long long* __restrict__ packed,
                            float* __restrict__ p2,
                            const float* __restrict__ proxies) {
    int i = blockIdx.x * blockDim.x + threadIdx.x;   // 128 blocks x 256 = 32768
    if (i < NROWS) packed[i] = 0xFFFFFFFFFFFFFFFFull;
    if (i < KP) {
        const float4* p = (const float4*)(proxies + (long)i * DIM);
        float s = 0.f;
        #pragma unroll
        for (int d = 0; d < DIM / 4; d++) {
            float4 v = p[d];
            s = fmaf(v.x, v.x, s);
            s = fmaf(v.y, v.y, s);
            s = fmaf(v.z, v.z, s);
            s = fmaf(v.w, v.w, s);
        }
        p2[i] = s;
    }
}

// One thread per row; k-chunk per blockIdx.y. x row lives in 128 VGPRs.
// score = p2[k] - 2*dot(x,p_k)  (monotone in true distance; /D and ||x||^2 dropped)
__global__ void __launch_bounds__(256)
argmin_kernel(const float* __restrict__ x,
              const float* __restrict__ proxies,
              const float* __restrict__ p2,
              unsigned long long* __restrict__ packed) {
    int n = blockIdx.x * 256 + threadIdx.x;   // grid.x = 128
    int k0 = blockIdx.y * KCHUNK;             // grid.y = NCHUNKS

    float4 xr[DIM / 4];
    const float4* xp = (const float4*)(x + (long)n * DIM);
    #pragma unroll
    for (int i = 0; i < DIM / 4; i++) xr[i] = xp[i];

    float best = 3.4e38f;
    int bestk = k0;
    for (int k = k0; k < k0 + KCHUNK; k++) {
        const float4* pk = (const float4*)(proxies + (long)k * DIM);  // wave-uniform addr
        float a0 = 0.f, a1 = 0.f, a2 = 0.f, a3 = 0.f;
        #pragma unroll
        for (int i = 0; i < DIM / 4; i += 4) {
            float4 q0 = pk[i+0], q1 = pk[i+1], q2 = pk[i+2], q3 = pk[i+3];
            a0 = fmaf(xr[i+0].x, q0.x, a0); a0 = fmaf(xr[i+0].y, q0.y, a0);
            a0 = fmaf(xr[i+0].z, q0.z, a0); a0 = fmaf(xr[i+0].w, q0.w, a0);
            a1 = fmaf(xr[i+1].x, q1.x, a1); a1 = fmaf(xr[i+1].y, q1.y, a1);
            a1 = fmaf(xr[i+1].z, q1.z, a1); a1 = fmaf(xr[i+1].w, q1.w, a1);
            a2 = fmaf(xr[i+2].x, q2.x, a2); a2 = fmaf(xr[i+2].y, q2.y, a2);
            a2 = fmaf(xr[i+2].z, q2.z, a2); a2 = fmaf(xr[i+2].w, q2.w, a2);
            a3 = fmaf(xr[i+3].x, q3.x, a3); a3 = fmaf(xr[i+3].y, q3.y, a3);
            a3 = fmaf(xr[i+3].z, q3.z, a3); a3 = fmaf(xr[i+3].w, q3.w, a3);
        }
        float dot = (a0 + a1) + (a2 + a3);
        float score = fmaf(-2.f, dot, p2[k]);
        if (score < best) { best = score; bestk = k; }   // strict <: first-min tie-break
    }
    unsigned long long key =
        ((unsigned long long)f2ord(best) << 32) | (unsigned int)bestk;
    atomicMin(&packed[n], key);   // device-scope; ties -> smaller k wins
}

// out[0 : N*D) = x ; out[N*D : 2*N*D) = proxies[idx]
__global__ void copy_x_proxy(const float4* __restrict__ x4,
                             const float4* __restrict__ prox4,
                             const unsigned long long* __restrict__ packed,
                             float4* __restrict__ out4) {
    int i = blockIdx.x * blockDim.x + threadIdx.x;   // 8192 blocks x 256 = 2*N*32
    const int R0 = NROWS * (DIM / 4);
    if (i < R0) {
        out4[i] = x4[i];
    } else {
        int j = i - R0;
        int n = j >> 5;           // DIM/4 = 32
        int d = j & 31;
        int k = (int)(unsigned int)(packed[n] & 0xFFFFFFFFull);
        out4[i] = prox4[(long)k * (DIM / 4) + d];
    }
}

// out[2*N*D : 2*N*D + N*C) = labels[idx] ; one block per row, 250 float4/row
__global__ void gather_labels(const float4* __restrict__ lab4,
                              const unsigned long long* __restrict__ packed,
                              float4* __restrict__ out4) {
    int n = blockIdx.x;
    int t = threadIdx.x;
    int k = (int)(unsigned int)(packed[n] & 0xFFFFFFFFull);
    if (t < CL / 4)
        out4[(long)n * (CL / 4) + t] = lab4[(long)k * (CL / 4) + t];
}

extern "C" void kernel_launch(void* const* d_in, const int* in_sizes, int n_in,
                              void* d_out, int out_size, void* d_ws, size_t ws_size,
                              hipStream_t stream) {
    const float* x       = (const float*)d_in[0];
    const float* proxies = (const float*)d_in[1];
    const float* labels  = (const float*)d_in[2];
    float* out = (float*)d_out;

    float* p2 = (float*)d_ws;                                        // 4000 floats
    unsigned long long* packed =
        (unsigned long long*)((char*)d_ws + 16384);                  // 32768 u64

    init_kernel<<<dim3(NROWS / 256), dim3(256), 0, stream>>>(packed, p2, proxies);

    dim3 g(NROWS / 256, NCHUNKS);
    argmin_kernel<<<g, dim3(256), 0, stream>>>(x, proxies, p2, packed);

    copy_x_proxy<<<dim3(2 * NROWS * (DIM / 4) / 256), dim3(256), 0, stream>>>(
        (const float4*)x, (const float4*)proxies, packed, (float4*)out);

    gather_labels<<<dim3(NROWS), dim3(256), 0, stream>>>(
        (const float4*)labels, packed, (float4*)(out + 2L * NROWS * DIM));
}